// Round 11
// baseline (424.287 us; speedup 1.0000x reference)
//
#include <hip/hip_runtime.h>
#include <hip/hip_bf16.h>

#define VOCAB   50000
#define BATCH   256
#define SEQ     512
#define NM1     1024
#define NM2     512
#define NEMB    256
#define KB1     782            /* ceil(50000/64) */
#define KPAD    (KB1*64)       /* 50048 */
#define SPLITK  64
#define NT      4              /* n-tiles of 256 */
#define HHALF   (KPAD/2)       /* 25024 vocab entries per hist block */

typedef __attribute__((ext_vector_type(8))) short short8;
typedef __attribute__((ext_vector_type(4))) float f32x4;

#define BOW_BYTES   ((size_t)BATCH * KPAD * 2)            /* 25,624,576 (bf16) */
#define PART_BYTES  ((size_t)SPLITK * BATCH * NM1 * 4)    /* 67,108,864 */

__device__ __forceinline__ short f2b(float x) {
    __hip_bfloat16 b = __float2bfloat16(x);
    return __builtin_bit_cast(short, b);
}
__device__ __forceinline__ unsigned short f2bu(float x) {
    __hip_bfloat16 b = __float2bfloat16(x);
    return __builtin_bit_cast(unsigned short, b);
}

// ---------------------------------------------------------------- histogram -> bf16 bow
__global__ __launch_bounds__(256) void BOW_hist2(const int* __restrict__ idx,
                                                 __hip_bfloat16* __restrict__ bow) {
    __shared__ unsigned int h[HHALF / 2];    // 12512 words = 50,048 B
    const int b    = blockIdx.x;
    const int row  = b >> 1;
    const int lo   = (b & 1) * HHALF;
    const int t    = threadIdx.x;

    for (int j = t; j < HHALF / 2; j += 256) h[j] = 0u;
    __syncthreads();

    #pragma unroll
    for (int u = 0; u < 2; u++) {
        int v = idx[row * SEQ + u * 256 + t];
        int d = v - lo;
        if ((unsigned)d < (unsigned)HHALF)
            atomicAdd(&h[d >> 1], (d & 1) ? 0x10000u : 1u);
    }
    __syncthreads();

    unsigned int* dst = (unsigned int*)(bow + (size_t)row * KPAD + lo);
    for (int j = t; j < HHALF / 2; j += 256) {
        unsigned int w   = h[j];
        unsigned int l16 = f2bu((float)(w & 0xFFFFu));
        unsigned int h16 = f2bu((float)(w >> 16));
        dst[j] = l16 | (h16 << 16);
    }
}

// ---------------------------------------------------------------- GEMM1
// partials[s][256][1024] += bow[256][Kchunk] * W1[256-chunk][Kchunk]^T  (bf16 MFMA)
// BM=256 (full M -> W1 read ONCE), BN=256 (A re-read only 4x), BK=64, SPLITK=64.
// grid = 64*4 = 256 blocks (1/CU), 1024 threads = 16 waves (4m x 4n), LDS 128 KB dbuf.
__global__ __launch_bounds__(1024) void BOW_gemm1(
        const __hip_bfloat16* __restrict__ bow,   // [256][KPAD], zero tail
        const float* __restrict__ W1,             // [1024][50000]
        float* __restrict__ partials)             // [SPLITK][256][1024]
{
    __shared__ __align__(16) __hip_bfloat16 As[2][256 * 64];  // 2 x 32 KB, swizzled
    __shared__ __align__(16) __hip_bfloat16 Bs[2][256 * 64];  // 2 x 32 KB, swizzled

    const int tid = threadIdx.x;
    // XCD swizzle: 256 blocks -> 32 consecutive swz per XCD; the 4 blocks sharing
    // a split (same A-chunk) get consecutive swz -> same XCD L2.
    const int swz = (blockIdx.x & 7) * 32 + (blockIdx.x >> 3);
    const int s   = swz >> 2;          // split 0..63
    const int nt  = swz & 3;           // n-tile 0..3
    const int n0  = nt * 256;

    // 782 kblocks over 64 splits: 14 splits of 13, 50 of 12
    const int kb_start = s * 12 + (s < 14 ? s : 14);
    const int kb_count = 12 + (s < 14 ? 1 : 0);

    const int lane = tid & 63;
    const int w    = tid >> 6;         // 0..15
    const int wm   = w >> 2;           // 0..3 (row group of 64)
    const int wn   = w & 3;            // 0..3 (col group of 64)

    f32x4 acc[4][4];
    #pragma unroll
    for (int m = 0; m < 4; m++)
        #pragma unroll
        for (int n = 0; n < 4; n++) acc[m][n] = (f32x4){0.f, 0.f, 0.f, 0.f};

    // B staging: 256 rows x 64 k f32; 4 threads/row, 16 f32 each (two 8-chunks)
    const int brow = tid >> 2;         // 0..255
    const int bq   = tid & 3;          // 0..3
    const int k8a  = bq * 2;           // first 8-chunk index
    const int bdsta = brow * 64 + ((k8a * 8)       ^ ((brow & 7) << 3));
    const int bdstb = brow * 64 + (((k8a + 1) * 8) ^ ((brow & 7) << 3));
    const float* wbase = W1 + (size_t)(n0 + brow) * VOCAB;

    auto STAGE_A = [&](int buf, int kb) {
        const int kg0 = kb * 64;
        #pragma unroll
        for (int i = 0; i < 2; i++) {
            int c   = i * 1024 + tid;
            int row = c >> 3;
            int k8  = c & 7;
            const __hip_bfloat16* src =
                bow + (size_t)row * KPAD + kg0 + ((k8 * 8) ^ ((row & 7) << 3));
            __builtin_amdgcn_global_load_lds(
                (const __attribute__((address_space(1))) void*)src,
                (__attribute__((address_space(3))) void*)&As[buf][c * 8], 16, 0, 0);
        }
    };
    auto B_LOAD = [&](int kb, float4& va0, float4& va1, float4& vb0, float4& vb1) {
        int kga = kb * 64 + k8a * 8;
        int kgb = kga + 8;
        va0 = (float4){0.f,0.f,0.f,0.f}; va1 = va0; vb0 = va0; vb1 = va0;
        if (kga < VOCAB) {   // 8-chunks fully valid or fully out (VOCAB % 8 == 0)
            const float* srca = wbase + kga;
            va0 = *reinterpret_cast<const float4*>(srca);
            va1 = *reinterpret_cast<const float4*>(srca + 4);
        }
        if (kgb < VOCAB) {
            const float* srcb = wbase + kgb;
            vb0 = *reinterpret_cast<const float4*>(srcb);
            vb1 = *reinterpret_cast<const float4*>(srcb + 4);
        }
    };
    auto B_WRITE = [&](int buf, float4 va0, float4 va1, float4 vb0, float4 vb1) {
        short8 p;
        p[0] = f2b(va0.x); p[1] = f2b(va0.y); p[2] = f2b(va0.z); p[3] = f2b(va0.w);
        p[4] = f2b(va1.x); p[5] = f2b(va1.y); p[6] = f2b(va1.z); p[7] = f2b(va1.w);
        *reinterpret_cast<short8*>(&Bs[buf][bdsta]) = p;
        short8 q;
        q[0] = f2b(vb0.x); q[1] = f2b(vb0.y); q[2] = f2b(vb0.z); q[3] = f2b(vb0.w);
        q[4] = f2b(vb1.x); q[5] = f2b(vb1.y); q[6] = f2b(vb1.z); q[7] = f2b(vb1.w);
        *reinterpret_cast<short8*>(&Bs[buf][bdstb]) = q;
    };
    auto COMPUTE = [&](int buf) {
        #pragma unroll
        for (int kk = 0; kk < 2; kk++) {
            const int kf = kk * 32 + ((lane >> 4) << 3);
            short8 a[4];
            #pragma unroll
            for (int m = 0; m < 4; m++) {
                int row = wm * 64 + m * 16 + (lane & 15);
                int e   = row * 64 + (kf ^ ((row & 7) << 3));
                a[m] = *reinterpret_cast<const short8*>(&As[buf][e]);
            }
            #pragma unroll
            for (int n = 0; n < 4; n++) {
                int row = wn * 64 + n * 16 + (lane & 15);
                int e   = row * 64 + (kf ^ ((row & 7) << 3));
                short8 b = *reinterpret_cast<const short8*>(&Bs[buf][e]);
                #pragma unroll
                for (int m = 0; m < 4; m++)
                    acc[m][n] = __builtin_amdgcn_mfma_f32_16x16x32_bf16(
                                    a[m], b, acc[m][n], 0, 0, 0);
            }
        }
    };

    // ---- prologue: fill buffer 0
    STAGE_A(0, kb_start);
    {
        float4 va0, va1, vb0, vb1;
        B_LOAD(kb_start, va0, va1, vb0, vb1);
        B_WRITE(0, va0, va1, vb0, vb1);
    }
    __syncthreads();

    // ---- 2-phase main loop
    int cur = 0;
    for (int kb = kb_start; kb < kb_start + kb_count - 1; ++kb) {
        int nxt = cur ^ 1;
        STAGE_A(nxt, kb + 1);              // async global->LDS, in flight over compute
        float4 va0, va1, vb0, vb1;
        B_LOAD(kb + 1, va0, va1, vb0, vb1);
        COMPUTE(cur);
        B_WRITE(nxt, va0, va1, vb0, vb1);
        __syncthreads();
        cur = nxt;
    }
    COMPUTE(cur);

    // ---- epilogue: write fp32 partial tile
    float* dst = partials + (size_t)s * (BATCH * NM1);
    #pragma unroll
    for (int m = 0; m < 4; m++) {
        #pragma unroll
        for (int n = 0; n < 4; n++) {
            int col = n0 + wn * 64 + n * 16 + (lane & 15);
            #pragma unroll
            for (int j = 0; j < 4; j++) {
                int rowi = wm * 64 + m * 16 + ((lane >> 4) * 4 + j);
                dst[(size_t)rowi * NM1 + col] = acc[m][n][j];
            }
        }
    }
}

// ---------------------------------------------------------------- reduce + bias + relu
__global__ void BOW_reduce1(const float* __restrict__ partials,
                            const float* __restrict__ b1,
                            float* __restrict__ h1) {
    int o = blockIdx.x * 256 + threadIdx.x;   // 262144 outputs
    int m = o & (NM1 - 1);
    float s = b1[m];
    #pragma unroll 8
    for (int sp = 0; sp < SPLITK; sp++) s += partials[(size_t)sp * (BATCH * NM1) + o];
    h1[o] = fmaxf(s, 0.f);
}

// ---------------------------------------------------------------- small fp32 GEMM
// out[256][N] = relu(A[256][K] @ Bw[N][K]^T + bias), tile 32x32, BK=32
__global__ void BOW_gemm_f32(const float* __restrict__ A,
                             const float* __restrict__ Bw,
                             const float* __restrict__ bias,
                             float* __restrict__ out,
                             int N, int K) {
    __shared__ float As[32][33];
    __shared__ float Bs[32][33];
    int tid = threadIdx.x;
    int i0 = blockIdx.y * 32, n0 = blockIdx.x * 32;
    int r = tid >> 5, c = tid & 31;
    int ty = tid >> 4, tx = tid & 15;
    float a2[2][2] = {{0.f, 0.f}, {0.f, 0.f}};

    for (int k0 = 0; k0 < K; k0 += 32) {
        #pragma unroll
        for (int rr = 0; rr < 4; rr++) {
            As[r + rr * 8][c] = A[(size_t)(i0 + r + rr * 8) * K + k0 + c];
            Bs[r + rr * 8][c] = Bw[(size_t)(n0 + r + rr * 8) * K + k0 + c];
        }
        __syncthreads();
        #pragma unroll
        for (int k = 0; k < 32; k++) {
            float av0 = As[ty * 2][k],     av1 = As[ty * 2 + 1][k];
            float bv0 = Bs[tx * 2][k],     bv1 = Bs[tx * 2 + 1][k];
            a2[0][0] += av0 * bv0; a2[0][1] += av0 * bv1;
            a2[1][0] += av1 * bv0; a2[1][1] += av1 * bv1;
        }
        __syncthreads();
    }
    #pragma unroll
    for (int ii = 0; ii < 2; ii++)
        #pragma unroll
        for (int nn = 0; nn < 2; nn++) {
            int i = i0 + ty * 2 + ii, n = n0 + tx * 2 + nn;
            out[(size_t)i * N + n] = fmaxf(a2[ii][nn] + bias[n], 0.f);
        }
}

// ---------------------------------------------------------------- launcher
extern "C" void kernel_launch(void* const* d_in, const int* in_sizes, int n_in,
                              void* d_out, int out_size, void* d_ws, size_t ws_size,
                              hipStream_t stream) {
    const int*   idx = (const int*)d_in[0];
    const float* W1  = (const float*)d_in[1];
    const float* b1  = (const float*)d_in[2];
    const float* W2  = (const float*)d_in[3];
    const float* b2  = (const float*)d_in[4];
    const float* W3  = (const float*)d_in[5];
    const float* b3  = (const float*)d_in[6];
    float* out = (float*)d_out;

    char* ws = (char*)d_ws;
    __hip_bfloat16* bow = (__hip_bfloat16*)ws;
    float* partials = (float*)(ws + BOW_BYTES);
    float* h1       = (float*)(ws + BOW_BYTES + PART_BYTES);
    float* h2       = h1 + BATCH * NM1;

    BOW_hist2<<<BATCH * 2, 256, 0, stream>>>(idx, bow);
    BOW_gemm1<<<SPLITK * NT, 1024, 0, stream>>>(bow, W1, partials);
    BOW_reduce1<<<(BATCH * NM1) / 256, 256, 0, stream>>>(partials, b1, h1);
    BOW_gemm_f32<<<dim3(NM2 / 32, BATCH / 32), 256, 0, stream>>>(h1, W2, b2, h2, NM2, NM1);
    BOW_gemm_f32<<<dim3(NEMB / 32, BATCH / 32), 256, 0, stream>>>(h2, W3, b3, out, NEMB, NM2);
}

// Round 14
// 420.715 us; speedup vs baseline: 1.0085x; 1.0085x over previous
//
#include <hip/hip_runtime.h>
#include <hip/hip_bf16.h>

#define VOCAB   50000
#define BATCH   256
#define SEQ     512
#define NM1     1024
#define NM2     512
#define NEMB    256
#define KB1     782            /* ceil(50000/64) */
#define KPAD    (KB1*64)       /* 50048 */
#define SPLITK  64
#define NT      8              /* n-tiles of 128 */
#define HHALF   (KPAD/2)       /* 25024 vocab entries per hist block */

typedef __attribute__((ext_vector_type(8))) short short8;
typedef __attribute__((ext_vector_type(4))) float f32x4;

#define BOW_BYTES   ((size_t)BATCH * KPAD * 2)            /* 25,624,576 (bf16) */
#define PART_BYTES  ((size_t)SPLITK * BATCH * NM1 * 4)    /* 67,108,864 */

__device__ __forceinline__ short f2b(float x) {
    __hip_bfloat16 b = __float2bfloat16(x);
    return __builtin_bit_cast(short, b);
}
__device__ __forceinline__ unsigned short f2bu(float x) {
    __hip_bfloat16 b = __float2bfloat16(x);
    return __builtin_bit_cast(unsigned short, b);
}

// ---------------------------------------------------------------- histogram -> bf16 bow
__global__ __launch_bounds__(256) void BOW_hist2(const int* __restrict__ idx,
                                                 __hip_bfloat16* __restrict__ bow) {
    __shared__ unsigned int h[HHALF / 2];    // 12512 words = 50,048 B
    const int b    = blockIdx.x;
    const int row  = b >> 1;
    const int lo   = (b & 1) * HHALF;
    const int t    = threadIdx.x;

    for (int j = t; j < HHALF / 2; j += 256) h[j] = 0u;
    __syncthreads();

    #pragma unroll
    for (int u = 0; u < 2; u++) {
        int v = idx[row * SEQ + u * 256 + t];
        int d = v - lo;
        if ((unsigned)d < (unsigned)HHALF)
            atomicAdd(&h[d >> 1], (d & 1) ? 0x10000u : 1u);
    }
    __syncthreads();

    unsigned int* dst = (unsigned int*)(bow + (size_t)row * KPAD + lo);
    for (int j = t; j < HHALF / 2; j += 256) {
        unsigned int w   = h[j];
        unsigned int l16 = f2bu((float)(w & 0xFFFFu));
        unsigned int h16 = f2bu((float)(w >> 16));
        dst[j] = l16 | (h16 << 16);
    }
}

// ---------------------------------------------------------------- GEMM1
// partials[s][256][1024] += bow[256][Kchunk] * W1[128-chunk][Kchunk]^T  (bf16 MFMA)
// BM=256 (W1 read ONCE), BN=128 (A re-read 8x, L2-served), BK=64, SPLITK=64.
// grid = 64*8 = 512 blocks -> 2/CU (the round-11 lesson: 1/CU serializes on the
// barrier drain). 512 threads = 8 waves (4m x 2n). LDS = A-dbuf 64 KB + B 16 KB
// = 80 KB/block -> exactly 2 blocks/CU of the 160 KB pool.
__global__ __launch_bounds__(512, 4) void BOW_gemm1(
        const __hip_bfloat16* __restrict__ bow,   // [256][KPAD], zero tail
        const float* __restrict__ W1,             // [1024][50000]
        float* __restrict__ partials)             // [SPLITK][256][1024]
{
    __shared__ __align__(16) __hip_bfloat16 As[2][256 * 64];  // 2 x 32 KB, swizzled
    __shared__ __align__(16) __hip_bfloat16 Bs[128 * 64];     // 16 KB, swizzled

    const int tid = threadIdx.x;
    // XCD-aware bijective swizzle (512 % 8 == 0): 64 consecutive swz per XCD,
    // so the 8 n-tiles sharing a split's A-chunk land on one XCD's L2.
    const int swz = (blockIdx.x & 7) * 64 + (blockIdx.x >> 3);
    const int s   = swz >> 3;          // split 0..63
    const int nt  = swz & 7;           // n-tile 0..7
    const int n0  = nt * 128;

    // 782 kblocks over 64 splits: 14 splits of 13, 50 of 12
    const int kb_start = s * 12 + (s < 14 ? s : 14);
    const int kb_count = 12 + (s < 14 ? 1 : 0);

    const int lane = tid & 63;
    const int w    = tid >> 6;         // 0..7
    const int wm   = w >> 1;           // 0..3 (row group of 64)
    const int wn   = w & 1;            // 0..1 (col group of 64)

    f32x4 acc[4][4];
    #pragma unroll
    for (int m = 0; m < 4; m++)
        #pragma unroll
        for (int n = 0; n < 4; n++) acc[m][n] = (f32x4){0.f, 0.f, 0.f, 0.f};

    // B staging: 128 rows x 64 k f32; 4 threads/row, 16 f32 each (two 8-chunks)
    const int brow = tid >> 2;         // 0..127
    const int k8a  = (tid & 3) * 2;    // first 8-chunk index
    const int bdsta = brow * 64 + ((k8a * 8)       ^ ((brow & 7) << 3));
    const int bdstb = brow * 64 + (((k8a + 1) * 8) ^ ((brow & 7) << 3));
    const float* wbase = W1 + (size_t)(n0 + brow) * VOCAB;

    auto STAGE_A = [&](int buf, int kb) {
        const int kg0 = kb * 64;
        #pragma unroll
        for (int i = 0; i < 4; i++) {
            int c   = i * 512 + tid;
            int row = c >> 3;
            int k8  = c & 7;
            const __hip_bfloat16* src =
                bow + (size_t)row * KPAD + kg0 + ((k8 * 8) ^ ((row & 7) << 3));
            __builtin_amdgcn_global_load_lds(
                (const __attribute__((address_space(1))) void*)src,
                (__attribute__((address_space(3))) void*)&As[buf][c * 8], 16, 0, 0);
        }
    };
    auto B_LOAD = [&](int kb, float4& va0, float4& va1, float4& vb0, float4& vb1) {
        int kga = kb * 64 + k8a * 8;
        int kgb = kga + 8;
        va0 = (float4){0.f,0.f,0.f,0.f}; va1 = va0; vb0 = va0; vb1 = va0;
        if (kga < VOCAB) {   // 8-chunks fully valid or fully out (VOCAB % 8 == 0)
            const float* srca = wbase + kga;
            va0 = *reinterpret_cast<const float4*>(srca);
            va1 = *reinterpret_cast<const float4*>(srca + 4);
        }
        if (kgb < VOCAB) {
            const float* srcb = wbase + kgb;
            vb0 = *reinterpret_cast<const float4*>(srcb);
            vb1 = *reinterpret_cast<const float4*>(srcb + 4);
        }
    };
    auto B_WRITE = [&](float4 va0, float4 va1, float4 vb0, float4 vb1) {
        short8 p;
        p[0] = f2b(va0.x); p[1] = f2b(va0.y); p[2] = f2b(va0.z); p[3] = f2b(va0.w);
        p[4] = f2b(va1.x); p[5] = f2b(va1.y); p[6] = f2b(va1.z); p[7] = f2b(va1.w);
        *reinterpret_cast<short8*>(&Bs[bdsta]) = p;
        short8 q;
        q[0] = f2b(vb0.x); q[1] = f2b(vb0.y); q[2] = f2b(vb0.z); q[3] = f2b(vb0.w);
        q[4] = f2b(vb1.x); q[5] = f2b(vb1.y); q[6] = f2b(vb1.z); q[7] = f2b(vb1.w);
        *reinterpret_cast<short8*>(&Bs[bdstb]) = q;
    };
    auto COMPUTE = [&](int buf) {
        #pragma unroll
        for (int kk = 0; kk < 2; kk++) {
            const int kf = kk * 32 + ((lane >> 4) << 3);
            short8 a[4];
            #pragma unroll
            for (int m = 0; m < 4; m++) {
                int row = wm * 64 + m * 16 + (lane & 15);
                int e   = row * 64 + (kf ^ ((row & 7) << 3));
                a[m] = *reinterpret_cast<const short8*>(&As[buf][e]);
            }
            #pragma unroll
            for (int n = 0; n < 4; n++) {
                int row = wn * 64 + n * 16 + (lane & 15);
                int e   = row * 64 + (kf ^ ((row & 7) << 3));
                short8 b = *reinterpret_cast<const short8*>(&Bs[e]);
                #pragma unroll
                for (int m = 0; m < 4; m++)
                    acc[m][n] = __builtin_amdgcn_mfma_f32_16x16x32_bf16(
                                    a[m], b, acc[m][n], 0, 0, 0);
            }
        }
    };

    // ---- prologue: fill A buffer 0 + B
    STAGE_A(0, kb_start);
    {
        float4 va0, va1, vb0, vb1;
        B_LOAD(kb_start, va0, va1, vb0, vb1);
        B_WRITE(va0, va1, vb0, vb1);
    }
    __syncthreads();

    // ---- main loop: A double-buffered (async prefetch), B single-buffered
    int cur = 0;
    for (int kb = kb_start; kb < kb_start + kb_count - 1; ++kb) {
        float4 va0, va1, vb0, vb1;
        B_LOAD(kb + 1, va0, va1, vb0, vb1);   // issue earliest: regs in flight
        STAGE_A(cur ^ 1, kb + 1);             // async global->LDS, other buffer
        COMPUTE(cur);                         // reads As[cur] + Bs (kb)
        __syncthreads();                      // all waves done reading Bs; A(nxt) drained
        B_WRITE(va0, va1, vb0, vb1);          // overwrite Bs with kb+1
        __syncthreads();                      // Bs ready
        cur ^= 1;
    }
    COMPUTE(cur);

    // ---- epilogue: write fp32 partial tile
    float* dst = partials + (size_t)s * (BATCH * NM1);
    #pragma unroll
    for (int m = 0; m < 4; m++) {
        #pragma unroll
        for (int n = 0; n < 4; n++) {
            int col = n0 + wn * 64 + n * 16 + (lane & 15);
            #pragma unroll
            for (int j = 0; j < 4; j++) {
                int rowi = wm * 64 + m * 16 + ((lane >> 4) * 4 + j);
                dst[(size_t)rowi * NM1 + col] = acc[m][n][j];
            }
        }
    }
}

// ---------------------------------------------------------------- reduce + bias + relu
__global__ void BOW_reduce1(const float* __restrict__ partials,
                            const float* __restrict__ b1,
                            float* __restrict__ h1) {
    int o = blockIdx.x * 256 + threadIdx.x;   // 262144 outputs
    int m = o & (NM1 - 1);
    float s = b1[m];
    #pragma unroll 8
    for (int sp = 0; sp < SPLITK; sp++) s += partials[(size_t)sp * (BATCH * NM1) + o];
    h1[o] = fmaxf(s, 0.f);
}

// ---------------------------------------------------------------- small fp32 GEMM
// out[256][N] = relu(A[256][K] @ Bw[N][K]^T + bias), tile 32x32, BK=32
__global__ void BOW_gemm_f32(const float* __restrict__ A,
                             const float* __restrict__ Bw,
                             const float* __restrict__ bias,
                             float* __restrict__ out,
                             int N, int K) {
    __shared__ float As[32][33];
    __shared__ float Bs[32][33];
    int tid = threadIdx.x;
    int i0 = blockIdx.y * 32, n0 = blockIdx.x * 32;
    int r = tid >> 5, c = tid & 31;
    int ty = tid >> 4, tx = tid & 15;
    float a2[2][2] = {{0.f, 0.f}, {0.f, 0.f}};

    for (int k0 = 0; k0 < K; k0 += 32) {
        #pragma unroll
        for (int rr = 0; rr < 4; rr++) {
            As[r + rr * 8][c] = A[(size_t)(i0 + r + rr * 8) * K + k0 + c];
            Bs[r + rr * 8][c] = Bw[(size_t)(n0 + r + rr * 8) * K + k0 + c];
        }
        __syncthreads();
        #pragma unroll
        for (int k = 0; k < 32; k++) {
            float av0 = As[ty * 2][k],     av1 = As[ty * 2 + 1][k];
            float bv0 = Bs[tx * 2][k],     bv1 = Bs[tx * 2 + 1][k];
            a2[0][0] += av0 * bv0; a2[0][1] += av0 * bv1;
            a2[1][0] += av1 * bv0; a2[1][1] += av1 * bv1;
        }
        __syncthreads();
    }
    #pragma unroll
    for (int ii = 0; ii < 2; ii++)
        #pragma unroll
        for (int nn = 0; nn < 2; nn++) {
            int i = i0 + ty * 2 + ii, n = n0 + tx * 2 + nn;
            out[(size_t)i * N + n] = fmaxf(a2[ii][nn] + bias[n], 0.f);
        }
}

// ---------------------------------------------------------------- launcher
extern "C" void kernel_launch(void* const* d_in, const int* in_sizes, int n_in,
                              void* d_out, int out_size, void* d_ws, size_t ws_size,
                              hipStream_t stream) {
    const int*   idx = (const int*)d_in[0];
    const float* W1  = (const float*)d_in[1];
    const float* b1  = (const float*)d_in[2];
    const float* W2  = (const float*)d_in[3];
    const float* b2  = (const float*)d_in[4];
    const float* W3  = (const float*)d_in[5];
    const float* b3  = (const float*)d_in[6];
    float* out = (float*)d_out;

    char* ws = (char*)d_ws;
    __hip_bfloat16* bow = (__hip_bfloat16*)ws;
    float* partials = (float*)(ws + BOW_BYTES);
    float* h1       = (float*)(ws + BOW_BYTES + PART_BYTES);
    float* h2       = h1 + BATCH * NM1;

    BOW_hist2<<<BATCH * 2, 256, 0, stream>>>(idx, bow);
    BOW_gemm1<<<SPLITK * NT, 512, 0, stream>>>(bow, W1, partials);
    BOW_reduce1<<<(BATCH * NM1) / 256, 256, 0, stream>>>(partials, b1, h1);
    BOW_gemm_f32<<<dim3(NM2 / 32, BATCH / 32), 256, 0, stream>>>(h1, W2, b2, h2, NM2, NM1);
    BOW_gemm_f32<<<dim3(NEMB / 32, BATCH / 32), 256, 0, stream>>>(h2, W3, b3, out, NEMB, NM2);
}